// Round 1
// baseline (582.699 us; speedup 1.0000x reference)
//
#include <hip/hip_runtime.h>
#include <hip/hip_bf16.h>

typedef __bf16 bf16x8 __attribute__((ext_vector_type(8)));
typedef float f32x4 __attribute__((ext_vector_type(4)));

#define LRELU(x) ((x) >= 0.f ? (x) : 0.2f * (x))

__device__ __forceinline__ unsigned short f2u(float f) {
    __hip_bfloat16 h = __float2bfloat16(f);
    return reinterpret_cast<unsigned short&>(h);
}

// ---------------- f32 -> bf16 convert (vector4, n must be multiple of 4) ----
__global__ void cvt_f32_bf16(const float* __restrict__ in,
                             __hip_bfloat16* __restrict__ out, int n4) {
    int stride = gridDim.x * blockDim.x;
    for (int i = blockIdx.x * blockDim.x + threadIdx.x; i < n4; i += stride) {
        float4 v = reinterpret_cast<const float4*>(in)[i];
        ushort4 o;
        o.x = f2u(v.x); o.y = f2u(v.y); o.z = f2u(v.z); o.w = f2u(v.w);
        reinterpret_cast<ushort4*>(out)[i] = o;
    }
}

// ---------------- fused GEMM + BN + LeakyReLU ------------------------------
// MODE 1: A=xk_bf16[M,512],  B=W1b[2048,512] -> values bf16 [M,2048]
// MODE 2: A=vals_bf16[M,2048] (+ xq broadcast = features), B=W2b[512,2048] -> s2 bf16 [M,512]
// MODE 3: A=s2_bf16[M,512],  B=W3b[64,512]  -> s3 f32 [M,64]
template <int MODE, int N, int K, int WAVES_M, int WAVES_N, int WM_FR, int WN_FR>
__global__ __launch_bounds__(WAVES_M * WAVES_N * 64)
void gemm_fused(const __hip_bfloat16* __restrict__ A,
                const __hip_bfloat16* __restrict__ Bw,
                const float* __restrict__ xq,
                __hip_bfloat16* __restrict__ out_bf,
                float* __restrict__ out_f,
                const float* __restrict__ Gg, const float* __restrict__ Gb,
                const float* __restrict__ Gm, const float* __restrict__ Gv) {
    const int lane = threadIdx.x & 63;
    const int wave = threadIdx.x >> 6;
    const int wm = wave / WAVES_N, wn = wave % WAVES_N;
    const int row0 = blockIdx.y * (WAVES_M * WM_FR * 16) + wm * (WM_FR * 16);
    const int col0 = blockIdx.x * (WAVES_N * WN_FR * 16) + wn * (WN_FR * 16);
    const int lr = lane & 15;   // A-row / B-col / D-col within fragment
    const int kg = lane >> 4;   // k-group 0..3

    f32x4 acc[WM_FR][WN_FR];
#pragma unroll
    for (int i = 0; i < WM_FR; ++i)
#pragma unroll
        for (int j = 0; j < WN_FR; ++j) acc[i][j] = (f32x4){0.f, 0.f, 0.f, 0.f};

    for (int k = 0; k < K; k += 32) {
        const int kk = k + kg * 8;
        bf16x8 a[WM_FR], b[WN_FR];
#pragma unroll
        for (int i = 0; i < WM_FR; ++i) {
            const int r = row0 + i * 16 + lr;
            if constexpr (MODE == 2) {
                bf16x8 v = *reinterpret_cast<const bf16x8*>(A + (size_t)r * K + kk);
                const float* xp = xq + ((r >> 11) << 11) + kk;
                float4 xa = *reinterpret_cast<const float4*>(xp);
                float4 xb = *reinterpret_cast<const float4*>(xp + 4);
                a[i][0] = (__bf16)((float)v[0] + xa.x);
                a[i][1] = (__bf16)((float)v[1] + xa.y);
                a[i][2] = (__bf16)((float)v[2] + xa.z);
                a[i][3] = (__bf16)((float)v[3] + xa.w);
                a[i][4] = (__bf16)((float)v[4] + xb.x);
                a[i][5] = (__bf16)((float)v[5] + xb.y);
                a[i][6] = (__bf16)((float)v[6] + xb.z);
                a[i][7] = (__bf16)((float)v[7] + xb.w);
            } else {
                a[i] = *reinterpret_cast<const bf16x8*>(A + (size_t)r * K + kk);
            }
        }
#pragma unroll
        for (int j = 0; j < WN_FR; ++j) {
            const int c = col0 + j * 16 + lr;
            b[j] = *reinterpret_cast<const bf16x8*>(Bw + (size_t)c * K + kk);
        }
#pragma unroll
        for (int i = 0; i < WM_FR; ++i)
#pragma unroll
            for (int j = 0; j < WN_FR; ++j)
                acc[i][j] = __builtin_amdgcn_mfma_f32_16x16x32_bf16(a[i], b[j], acc[i][j], 0, 0, 0);
    }

    // epilogue: BN (eval) + LeakyReLU, layout D: col=lane&15, row=(lane>>4)*4+reg
#pragma unroll
    for (int j = 0; j < WN_FR; ++j) {
        const int c = col0 + j * 16 + lr;
        const float sc = Gg[c] * rsqrtf(Gv[c] + 1e-5f);
        const float tc = Gb[c] - Gm[c] * sc;
#pragma unroll
        for (int i = 0; i < WM_FR; ++i) {
#pragma unroll
            for (int rI = 0; rI < 4; ++rI) {
                const int rrow = row0 + i * 16 + kg * 4 + rI;
                float val = acc[i][j][rI] * sc + tc;
                val = LRELU(val);
                const size_t idx = (size_t)rrow * N + c;
                if constexpr (MODE == 1) {
                    out_bf[idx] = __float2bfloat16(val);
                } else if constexpr (MODE == 2) {
                    out_bf[idx] = __float2bfloat16(val);
                } else {
                    out_f[idx] = val;
                }
            }
        }
    }
}

// ---------------- layer 4 (dot-64 + BN + lrelu) + softmax over N=2048 ------
__global__ void l4_softmax(const float* __restrict__ s3, const float* __restrict__ W4,
                           const float* __restrict__ g4, const float* __restrict__ b4,
                           const float* __restrict__ m4, const float* __restrict__ v4,
                           float* __restrict__ scores) {
    __shared__ float logits[2048];
    __shared__ float red[256];
    __shared__ float w4s[64];
    const int b = blockIdx.x;
    const int tid = threadIdx.x;
    if (tid < 64) w4s[tid] = W4[tid];
    __syncthreads();
    const float scl = g4[0] * rsqrtf(v4[0] + 1e-5f);
    const float tc = b4[0] - m4[0] * scl;
    float lmax = -1e30f;
#pragma unroll
    for (int it = 0; it < 8; ++it) {
        const int n = tid + it * 256;
        const float4* p = reinterpret_cast<const float4*>(s3 + ((size_t)(b * 2048 + n)) * 64);
        float dot = 0.f;
#pragma unroll
        for (int q = 0; q < 16; ++q) {
            float4 v = p[q];
            dot += v.x * w4s[4 * q] + v.y * w4s[4 * q + 1] + v.z * w4s[4 * q + 2] + v.w * w4s[4 * q + 3];
        }
        float val = dot * scl + tc;
        val = LRELU(val);
        logits[n] = val;
        lmax = fmaxf(lmax, val);
    }
    red[tid] = lmax;
    __syncthreads();
    for (int s = 128; s > 0; s >>= 1) {
        if (tid < s) red[tid] = fmaxf(red[tid], red[tid + s]);
        __syncthreads();
    }
    const float gmax = red[0];
    __syncthreads();
    float lsum = 0.f;
#pragma unroll
    for (int it = 0; it < 8; ++it) {
        const int n = tid + it * 256;
        float e = expf(logits[n] - gmax);
        logits[n] = e;
        lsum += e;
    }
    red[tid] = lsum;
    __syncthreads();
    for (int s = 128; s > 0; s >>= 1) {
        if (tid < s) red[tid] += red[tid + s];
        __syncthreads();
    }
    const float inv = 1.f / red[0];
#pragma unroll
    for (int it = 0; it < 8; ++it) {
        const int n = tid + it * 256;
        scores[b * 2048 + n] = logits[n] * inv;
    }
}

// ---------------- pooling: partial over n-chunks, then reduce --------------
__global__ void pool_partial(const __hip_bfloat16* __restrict__ vals,
                             const float* __restrict__ scores,
                             float* __restrict__ partial) {
    const int b = blockIdx.y, nc = blockIdx.x;  // 32 chunks of 64 rows
    const int e0 = threadIdx.x * 8;
    float acc[8] = {0, 0, 0, 0, 0, 0, 0, 0};
    const size_t base = ((size_t)b * 2048 + nc * 64) * 2048;
    for (int i = 0; i < 64; ++i) {
        const float sc = scores[b * 2048 + nc * 64 + i];
        bf16x8 v = *reinterpret_cast<const bf16x8*>(vals + base + (size_t)i * 2048 + e0);
#pragma unroll
        for (int j = 0; j < 8; ++j) acc[j] += sc * (float)v[j];
    }
    float* p = partial + ((size_t)(b * 32 + nc)) * 2048 + e0;
#pragma unroll
    for (int j = 0; j < 8; ++j) p[j] = acc[j];
}

__global__ void pool_reduce(const float* __restrict__ partial, float* __restrict__ out) {
    const int i = blockIdx.x * blockDim.x + threadIdx.x;  // 0..32767
    const int b = i >> 11, e = i & 2047;
    float s = 0.f;
#pragma unroll
    for (int nc = 0; nc < 32; ++nc) s += partial[((size_t)(b * 32 + nc)) * 2048 + e];
    out[i] = s;
}

// ---------------------------------------------------------------------------
extern "C" void kernel_launch(void* const* d_in, const int* in_sizes, int n_in,
                              void* d_out, int out_size, void* d_ws, size_t ws_size,
                              hipStream_t stream) {
    const float* xq = (const float*)d_in[0];
    const float* xk = (const float*)d_in[1];
    const float* W1 = (const float*)d_in[2];
    const float* W2 = (const float*)d_in[3];
    const float* W3 = (const float*)d_in[4];
    const float* W4 = (const float*)d_in[5];
    const float* g1 = (const float*)d_in[6], *b1 = (const float*)d_in[7];
    const float* m1 = (const float*)d_in[8], *v1 = (const float*)d_in[9];
    const float* g2 = (const float*)d_in[10], *b2 = (const float*)d_in[11];
    const float* m2 = (const float*)d_in[12], *v2 = (const float*)d_in[13];
    const float* g3 = (const float*)d_in[14], *b3 = (const float*)d_in[15];
    const float* m3 = (const float*)d_in[16], *v3 = (const float*)d_in[17];
    const float* g4 = (const float*)d_in[18], *b4 = (const float*)d_in[19];
    const float* m4 = (const float*)d_in[20], *v4 = (const float*)d_in[21];

    const int M = 32768;  // B*N = 16*2048

    char* ws = (char*)d_ws;
    size_t off = 0;
    auto alloc = [&](size_t bytes) {
        void* p = ws + off;
        off += (bytes + 255) & ~(size_t)255;
        return p;
    };
    __hip_bfloat16* xkb   = (__hip_bfloat16*)alloc((size_t)M * 512 * 2);
    __hip_bfloat16* w1b   = (__hip_bfloat16*)alloc((size_t)2048 * 512 * 2);
    __hip_bfloat16* w2b   = (__hip_bfloat16*)alloc((size_t)512 * 2048 * 2);
    __hip_bfloat16* w3b   = (__hip_bfloat16*)alloc((size_t)64 * 512 * 2);
    __hip_bfloat16* valsb = (__hip_bfloat16*)alloc((size_t)M * 2048 * 2);
    __hip_bfloat16* s2b   = (__hip_bfloat16*)alloc((size_t)M * 512 * 2);
    float* s3f            = (float*)alloc((size_t)M * 64 * 4);
    float* scores         = (float*)alloc((size_t)16 * 2048 * 4);
    float* partial        = (float*)alloc((size_t)16 * 32 * 2048 * 4);

    // converts
    cvt_f32_bf16<<<4096, 256, 0, stream>>>(xk, xkb, M * 512 / 4);
    cvt_f32_bf16<<<1024, 256, 0, stream>>>(W1, w1b, 2048 * 512 / 4);
    cvt_f32_bf16<<<1024, 256, 0, stream>>>(W2, w2b, 512 * 2048 / 4);
    cvt_f32_bf16<<<32, 256, 0, stream>>>(W3, w3b, 64 * 512 / 4);

    // GEMM1: values = lrelu(bn1(xk @ W1^T))        [M,2048]
    gemm_fused<1, 2048, 512, 2, 2, 4, 4>
        <<<dim3(2048 / 128, M / 128), 256, 0, stream>>>(
            xkb, w1b, xq, valsb, nullptr, g1, b1, m1, v1);

    // GEMM2: s2 = lrelu(bn2((values + xq) @ W2^T)) [M,512]
    gemm_fused<2, 512, 2048, 2, 2, 4, 4>
        <<<dim3(512 / 128, M / 128), 256, 0, stream>>>(
            valsb, w2b, xq, s2b, nullptr, g2, b2, m2, v2);

    // GEMM3: s3 = lrelu(bn3(s2 @ W3^T))            [M,64] f32
    gemm_fused<3, 64, 512, 2, 2, 4, 2>
        <<<dim3(64 / 64, M / 128), 256, 0, stream>>>(
            s2b, w3b, nullptr, nullptr, s3f, g3, b3, m3, v3);

    // layer4 + softmax over N per batch
    l4_softmax<<<16, 256, 0, stream>>>(s3f, W4, g4, b4, m4, v4, scores);

    // pooling
    pool_partial<<<dim3(32, 16), 256, 0, stream>>>(valsb, scores, partial);
    pool_reduce<<<128, 256, 0, stream>>>(partial, (float*)d_out);
}

// Round 2
// 281.612 us; speedup vs baseline: 2.0692x; 2.0692x over previous
//
#include <hip/hip_runtime.h>
#include <hip/hip_bf16.h>

typedef __bf16 bf16x8 __attribute__((ext_vector_type(8)));
typedef float f32x4 __attribute__((ext_vector_type(4)));
typedef __attribute__((address_space(3))) void lds_void_t;
typedef __attribute__((address_space(1))) void gbl_void_t;

#define LRELU(x) ((x) >= 0.f ? (x) : 0.2f * (x))

__device__ __forceinline__ void gload16(void* lds_uniform, const void* gsrc) {
    __builtin_amdgcn_global_load_lds((const gbl_void_t*)gsrc, (lds_void_t*)lds_uniform,
                                     16, 0, 0);
}

__device__ __forceinline__ unsigned short f2u(float f) {
    __hip_bfloat16 h = __float2bfloat16(f);
    return reinterpret_cast<unsigned short&>(h);
}

// ---------------- f32 -> bf16 convert (vector4) ----------------------------
__global__ void cvt_f32_bf16(const float* __restrict__ in,
                             __hip_bfloat16* __restrict__ out, int n4) {
    int stride = gridDim.x * blockDim.x;
    for (int i = blockIdx.x * blockDim.x + threadIdx.x; i < n4; i += stride) {
        float4 v = reinterpret_cast<const float4*>(in)[i];
        ushort4 o;
        o.x = f2u(v.x); o.y = f2u(v.y); o.z = f2u(v.z); o.w = f2u(v.w);
        reinterpret_cast<ushort4*>(out)[i] = o;
    }
}

// ---------------- m97-structure LDS GEMM + fused epilogue ------------------
// 128x128 tile, BK=32, 4 waves (2x2), 4x4 fragments of 16x16x32 bf16 MFMA.
// MODE 1: out = bf16( lrelu(bn1(A@B^T)) + xq[b][col] )   (features)
// MODE 2: out = bf16( lrelu(bn2(A@B^T)) )                (s2)
template <int N, int K, int MODE>
__global__ __launch_bounds__(256)
void gemm_lds(const __hip_bfloat16* __restrict__ A,
              const __hip_bfloat16* __restrict__ Bw,
              const float* __restrict__ xq,
              __hip_bfloat16* __restrict__ out,
              const float* __restrict__ Gg, const float* __restrict__ Gb,
              const float* __restrict__ Gm, const float* __restrict__ Gv) {
    __shared__ __hip_bfloat16 lA[128 * 32];
    __shared__ __hip_bfloat16 lB[128 * 32];
    const int tid = threadIdx.x;
    const int lane = tid & 63;
    const int wv = tid >> 6;          // 0..3
    const int wm = wv >> 1, wn = wv & 1;
    const int row0 = blockIdx.y * 128;
    const int col0 = blockIdx.x * 128;
    const int lr = lane & 15, kg = lane >> 4;

    // staging: issue q=wv*2+t covers LDS elements [q*512, q*512+512)
    // lane l supplies elements q*512 + l*8 .. +8  -> row q*16 + l/4, k (l%4)*8
    const int srow = lane >> 2;
    const int sk = (lane & 3) << 3;
    const __hip_bfloat16* Ag = A + (size_t)(row0 + wv * 32 + srow) * K + sk;
    const __hip_bfloat16* Bg = Bw + (size_t)(col0 + wv * 32 + srow) * K + sk;
    __hip_bfloat16* lAp = lA + wv * 1024;
    __hip_bfloat16* lBp = lB + wv * 1024;

    f32x4 acc[4][4];
#pragma unroll
    for (int i = 0; i < 4; ++i)
#pragma unroll
        for (int j = 0; j < 4; ++j) acc[i][j] = (f32x4){0.f, 0.f, 0.f, 0.f};

    for (int k = 0; k < K; k += 32) {
        gload16(lAp,       Ag + k);
        gload16(lAp + 512, Ag + k + (size_t)16 * K);
        gload16(lBp,       Bg + k);
        gload16(lBp + 512, Bg + k + (size_t)16 * K);
        asm volatile("s_waitcnt vmcnt(0)" ::: "memory");
        __syncthreads();

        bf16x8 af[4], bfr[4];
#pragma unroll
        for (int i = 0; i < 4; ++i)
            af[i] = *reinterpret_cast<const bf16x8*>(&lA[(wm * 64 + i * 16 + lr) * 32 + kg * 8]);
#pragma unroll
        for (int j = 0; j < 4; ++j)
            bfr[j] = *reinterpret_cast<const bf16x8*>(&lB[(wn * 64 + j * 16 + lr) * 32 + kg * 8]);
#pragma unroll
        for (int i = 0; i < 4; ++i)
#pragma unroll
            for (int j = 0; j < 4; ++j)
                acc[i][j] = __builtin_amdgcn_mfma_f32_16x16x32_bf16(af[i], bfr[j], acc[i][j], 0, 0, 0);
        __syncthreads();
    }

    // epilogue: D layout col=lane&15, row=(lane>>4)*4+reg
    const int bq = row0 >> 11;  // batch index (128 rows always within one batch)
#pragma unroll
    for (int j = 0; j < 4; ++j) {
        const int c = col0 + wn * 64 + j * 16 + lr;
        const float sc = Gg[c] * rsqrtf(Gv[c] + 1e-5f);
        const float tc = Gb[c] - Gm[c] * sc;
        float xqv = 0.f;
        if constexpr (MODE == 1) xqv = xq[bq * 2048 + c];
#pragma unroll
        for (int i = 0; i < 4; ++i) {
#pragma unroll
            for (int rI = 0; rI < 4; ++rI) {
                const int r = row0 + wm * 64 + i * 16 + kg * 4 + rI;
                float val = acc[i][j][rI] * sc + tc;
                val = LRELU(val) + xqv;
                out[(size_t)r * N + c] = __float2bfloat16(val);
            }
        }
    }
}

// ---------------- GEMM3 (M x 64, K=512) fused with layer-4 + bn4 ----------
// 4 waves; each wave owns 32 rows x all 64 cols; direct global fragment loads.
__global__ __launch_bounds__(256)
void gemm3_l4(const __hip_bfloat16* __restrict__ A,    // s2b [M,512]
              const __hip_bfloat16* __restrict__ W3b,  // [64,512]
              const float* __restrict__ W4,            // [64]
              const float* __restrict__ g3, const float* __restrict__ b3,
              const float* __restrict__ m3, const float* __restrict__ v3,
              const float* __restrict__ g4, const float* __restrict__ b4,
              const float* __restrict__ m4, const float* __restrict__ v4,
              float* __restrict__ logits) {
    const int lane = threadIdx.x & 63;
    const int wv = threadIdx.x >> 6;
    const int row0 = blockIdx.x * 128 + wv * 32;
    const int lr = lane & 15, kg = lane >> 4;

    f32x4 acc[2][4];
#pragma unroll
    for (int i = 0; i < 2; ++i)
#pragma unroll
        for (int j = 0; j < 4; ++j) acc[i][j] = (f32x4){0.f, 0.f, 0.f, 0.f};

    for (int k = 0; k < 512; k += 32) {
        const int kk = k + kg * 8;
        bf16x8 a[2], b[4];
#pragma unroll
        for (int i = 0; i < 2; ++i)
            a[i] = *reinterpret_cast<const bf16x8*>(A + (size_t)(row0 + i * 16 + lr) * 512 + kk);
#pragma unroll
        for (int j = 0; j < 4; ++j)
            b[j] = *reinterpret_cast<const bf16x8*>(W3b + (size_t)(j * 16 + lr) * 512 + kk);
#pragma unroll
        for (int i = 0; i < 2; ++i)
#pragma unroll
            for (int j = 0; j < 4; ++j)
                acc[i][j] = __builtin_amdgcn_mfma_f32_16x16x32_bf16(a[i], b[j], acc[i][j], 0, 0, 0);
    }

    const float sc4 = g4[0] * rsqrtf(v4[0] + 1e-5f);
    const float tc4 = b4[0] - m4[0] * sc4;
#pragma unroll
    for (int i = 0; i < 2; ++i) {
        float t[4] = {0.f, 0.f, 0.f, 0.f};
#pragma unroll
        for (int j = 0; j < 4; ++j) {
            const int c = j * 16 + lr;
            const float sc = g3[c] * rsqrtf(v3[c] + 1e-5f);
            const float tc = b3[c] - m3[c] * sc;
            const float w4c = W4[c];
#pragma unroll
            for (int rI = 0; rI < 4; ++rI) {
                float v = acc[i][j][rI] * sc + tc;
                t[rI] += LRELU(v) * w4c;
            }
        }
#pragma unroll
        for (int m = 1; m < 16; m <<= 1)
#pragma unroll
            for (int rI = 0; rI < 4; ++rI) t[rI] += __shfl_xor(t[rI], m, 64);
        if (lr == 0) {
#pragma unroll
            for (int rI = 0; rI < 4; ++rI) {
                float lg = t[rI] * sc4 + tc4;
                logits[row0 + i * 16 + kg * 4 + rI] = LRELU(lg);
            }
        }
    }
}

// ---------------- softmax over N=2048 per batch ----------------------------
__global__ void softmax2048(const float* __restrict__ logits, float* __restrict__ scores) {
    __shared__ float sh[2048];
    __shared__ float red[256];
    const int b = blockIdx.x, tid = threadIdx.x;
    float lmax = -1e30f;
#pragma unroll
    for (int it = 0; it < 8; ++it) {
        const int n = tid + it * 256;
        float v = logits[b * 2048 + n];
        sh[n] = v;
        lmax = fmaxf(lmax, v);
    }
    red[tid] = lmax;
    __syncthreads();
    for (int s = 128; s > 0; s >>= 1) {
        if (tid < s) red[tid] = fmaxf(red[tid], red[tid + s]);
        __syncthreads();
    }
    const float gmax = red[0];
    __syncthreads();
    float lsum = 0.f;
#pragma unroll
    for (int it = 0; it < 8; ++it) {
        const int n = tid + it * 256;
        float e = expf(sh[n] - gmax);
        sh[n] = e;
        lsum += e;
    }
    red[tid] = lsum;
    __syncthreads();
    for (int s = 128; s > 0; s >>= 1) {
        if (tid < s) red[tid] += red[tid + s];
        __syncthreads();
    }
    const float inv = 1.f / red[0];
#pragma unroll
    for (int it = 0; it < 8; ++it) {
        const int n = tid + it * 256;
        scores[b * 2048 + n] = sh[n] * inv;
    }
}

// ---------------- pooling over features, then subtract xq ------------------
// out[b,e] = sum_n features[b,n,e]*scores[b,n] - xq[b,e]   (since sum scores = 1)
__global__ void pool_partial(const __hip_bfloat16* __restrict__ feats,
                             const float* __restrict__ scores,
                             float* __restrict__ partial) {
    const int b = blockIdx.y, nc = blockIdx.x;  // 32 chunks of 64 rows
    const int e0 = threadIdx.x * 8;
    float acc[8] = {0, 0, 0, 0, 0, 0, 0, 0};
    const size_t base = ((size_t)b * 2048 + nc * 64) * 2048;
    for (int i = 0; i < 64; ++i) {
        const float sc = scores[b * 2048 + nc * 64 + i];
        bf16x8 v = *reinterpret_cast<const bf16x8*>(feats + base + (size_t)i * 2048 + e0);
#pragma unroll
        for (int j = 0; j < 8; ++j) acc[j] += sc * (float)v[j];
    }
    float* p = partial + ((size_t)(b * 32 + nc)) * 2048 + e0;
#pragma unroll
    for (int j = 0; j < 8; ++j) p[j] = acc[j];
}

__global__ void pool_reduce(const float* __restrict__ partial,
                            const float* __restrict__ xq,
                            float* __restrict__ out) {
    const int i = blockIdx.x * blockDim.x + threadIdx.x;  // 0..32767
    const int b = i >> 11, e = i & 2047;
    float s = 0.f;
#pragma unroll
    for (int nc = 0; nc < 32; ++nc) s += partial[((size_t)(b * 32 + nc)) * 2048 + e];
    out[i] = s - xq[i];
}

// ---------------------------------------------------------------------------
extern "C" void kernel_launch(void* const* d_in, const int* in_sizes, int n_in,
                              void* d_out, int out_size, void* d_ws, size_t ws_size,
                              hipStream_t stream) {
    const float* xq = (const float*)d_in[0];
    const float* xk = (const float*)d_in[1];
    const float* W1 = (const float*)d_in[2];
    const float* W2 = (const float*)d_in[3];
    const float* W3 = (const float*)d_in[4];
    const float* W4 = (const float*)d_in[5];
    const float* g1 = (const float*)d_in[6], *b1 = (const float*)d_in[7];
    const float* m1 = (const float*)d_in[8], *v1 = (const float*)d_in[9];
    const float* g2 = (const float*)d_in[10], *b2 = (const float*)d_in[11];
    const float* m2 = (const float*)d_in[12], *v2 = (const float*)d_in[13];
    const float* g3 = (const float*)d_in[14], *b3 = (const float*)d_in[15];
    const float* m3 = (const float*)d_in[16], *v3 = (const float*)d_in[17];
    const float* g4 = (const float*)d_in[18], *b4 = (const float*)d_in[19];
    const float* m4 = (const float*)d_in[20], *v4 = (const float*)d_in[21];

    const int M = 32768;  // B*N = 16*2048

    char* ws = (char*)d_ws;
    size_t off = 0;
    auto alloc = [&](size_t bytes) {
        void* p = ws + off;
        off += (bytes + 255) & ~(size_t)255;
        return p;
    };
    __hip_bfloat16* xkb   = (__hip_bfloat16*)alloc((size_t)M * 512 * 2);
    __hip_bfloat16* w1b   = (__hip_bfloat16*)alloc((size_t)2048 * 512 * 2);
    __hip_bfloat16* w2b   = (__hip_bfloat16*)alloc((size_t)512 * 2048 * 2);
    __hip_bfloat16* w3b   = (__hip_bfloat16*)alloc((size_t)64 * 512 * 2);
    __hip_bfloat16* featb = (__hip_bfloat16*)alloc((size_t)M * 2048 * 2);
    __hip_bfloat16* s2b   = (__hip_bfloat16*)alloc((size_t)M * 512 * 2);
    float* logits         = (float*)alloc((size_t)M * 4);
    float* scores         = (float*)alloc((size_t)16 * 2048 * 4);
    float* partial        = (float*)alloc((size_t)16 * 32 * 2048 * 4);

    // converts
    cvt_f32_bf16<<<4096, 256, 0, stream>>>(xk, xkb, M * 512 / 4);
    cvt_f32_bf16<<<1024, 256, 0, stream>>>(W1, w1b, 2048 * 512 / 4);
    cvt_f32_bf16<<<1024, 256, 0, stream>>>(W2, w2b, 512 * 2048 / 4);
    cvt_f32_bf16<<<32, 256, 0, stream>>>(W3, w3b, 64 * 512 / 4);

    // GEMM1: features = lrelu(bn1(xk @ W1^T)) + xq   [M,2048] bf16
    gemm_lds<2048, 512, 1><<<dim3(16, 256), 256, 0, stream>>>(
        xkb, w1b, xq, featb, g1, b1, m1, v1);

    // GEMM2: s2 = lrelu(bn2(features @ W2^T))        [M,512] bf16
    gemm_lds<512, 2048, 2><<<dim3(4, 256), 256, 0, stream>>>(
        featb, w2b, nullptr, s2b, g2, b2, m2, v2);

    // GEMM3 + layer4: logits [M] f32
    gemm3_l4<<<256, 256, 0, stream>>>(s2b, w3b, W4,
                                      g3, b3, m3, v3, g4, b4, m4, v4, logits);

    // softmax over N per batch
    softmax2048<<<16, 256, 0, stream>>>(logits, scores);

    // pooling (+ subtract xq)
    pool_partial<<<dim3(32, 16), 256, 0, stream>>>(featb, scores, partial);
    pool_reduce<<<128, 256, 0, stream>>>(partial, xq, (float*)d_out);
}

// Round 3
// 244.982 us; speedup vs baseline: 2.3785x; 1.1495x over previous
//
#include <hip/hip_runtime.h>
#include <hip/hip_bf16.h>

typedef __bf16 bf16x8 __attribute__((ext_vector_type(8)));
typedef float f32x4 __attribute__((ext_vector_type(4)));
typedef __attribute__((address_space(3))) void lds_void_t;
typedef __attribute__((address_space(1))) void gbl_void_t;

#define LRELU(x) ((x) >= 0.f ? (x) : 0.2f * (x))

__device__ __forceinline__ void gload16(void* lds_uniform, const void* gsrc) {
    __builtin_amdgcn_global_load_lds((const gbl_void_t*)gsrc, (lds_void_t*)lds_uniform,
                                     16, 0, 0);
}

__device__ __forceinline__ unsigned short f2u(float f) {
    __hip_bfloat16 h = __float2bfloat16(f);
    return reinterpret_cast<unsigned short&>(h);
}

// ---------------- f32 -> bf16 convert (vector4) ----------------------------
__global__ void cvt_f32_bf16(const float* __restrict__ in,
                             __hip_bfloat16* __restrict__ out, int n4) {
    int stride = gridDim.x * blockDim.x;
    for (int i = blockIdx.x * blockDim.x + threadIdx.x; i < n4; i += stride) {
        float4 v = reinterpret_cast<const float4*>(in)[i];
        ushort4 o;
        o.x = f2u(v.x); o.y = f2u(v.y); o.z = f2u(v.z); o.w = f2u(v.w);
        reinterpret_cast<ushort4*>(out)[i] = o;
    }
}

// ---------------- 256x256 tile GEMM, BK=32, triple-buffer, counted vmcnt ---
// 8 waves (2M x 4N), per-wave output 128x64 (8x4 fragments 16x16x32 bf16).
// LDS: 3 buffers x (A 8192 + B 8192 elements) = 96 KB.
// Staging: global_load_lds 16B/lane, chunk-XOR swizzle applied on the
// GLOBAL source address (LDS dest stays linear), same XOR on ds_read.
// Pipeline: STAGE(t+2) at top of iter t; vmcnt(8) -> tile t landed while
// t+1/t+2 stay in flight (never drain to 0 in the loop).
// MODE 1: out = bf16( lrelu(bn(A@B^T)) + xq[b][col] )   (features)
// MODE 2: out = bf16( lrelu(bn(A@B^T)) )                (s2)
template <int N, int K, int MODE>
__global__ __launch_bounds__(512, 2)
void gemm256(const __hip_bfloat16* __restrict__ A,
             const __hip_bfloat16* __restrict__ Bw,
             const float* __restrict__ xq,
             __hip_bfloat16* __restrict__ out,
             const float* __restrict__ Gg, const float* __restrict__ Gb,
             const float* __restrict__ Gm, const float* __restrict__ Gv) {
    __shared__ __hip_bfloat16 sm[3 * 16384];

    // XCD-aware block swizzle (nwg % 8 == 0 guaranteed by launch config)
    const int nwg = gridDim.x;
    const int cpx = nwg >> 3;
    const int bid = blockIdx.x;
    const int orig = (bid & 7) * cpx + (bid >> 3);
    constexpr int NCB = N / 256;
    const int rowblk = orig / NCB;
    const int colblk = orig % NCB;
    const int row0 = rowblk * 256, col0 = colblk * 256;

    const int tid = threadIdx.x;
    const int lane = tid & 63;
    const int wv = tid >> 6;          // 0..7
    const int wm = wv >> 2, wn = wv & 3;
    const int lr = lane & 15, kg = lane >> 4;

    // ---- staging source addresses (pre-swizzled global chunks) ----
    const int srow = tid >> 2;        // dest row (mod 128)
    const int sc = tid & 3;           // dest 16B-chunk position
    const int kch = ((sc ^ ((srow >> 1) & 3)) << 3);  // source k-chunk (elements)
    const __hip_bfloat16* As0 = A + (size_t)(row0 + srow) * K + kch;
    const __hip_bfloat16* As1 = A + (size_t)(row0 + 128 + srow) * K + kch;
    const __hip_bfloat16* Bs0 = Bw + (size_t)(col0 + srow) * K + kch;
    const __hip_bfloat16* Bs1 = Bw + (size_t)(col0 + 128 + srow) * K + kch;

    auto STAGE = [&](int b, int k0) {
        __hip_bfloat16* la = sm + b * 16384 + wv * 512;  // per-wave uniform base
        __hip_bfloat16* lb = la + 8192;
        gload16(la,        As0 + k0);
        gload16(la + 4096, As1 + k0);
        gload16(lb,        Bs0 + k0);
        gload16(lb + 4096, Bs1 + k0);
    };

    // ---- ds_read fragment offsets (swizzled chunk) ----
    const int f = (lr >> 1) & 3;
    const int koff = ((kg ^ f) << 3);
    const int aoff = (wm * 128 + lr) * 32 + koff;          // A: elements
    const int boff = 8192 + (wn * 64 + lr) * 32 + koff;    // B: elements

    f32x4 acc[8][4];
#pragma unroll
    for (int i = 0; i < 8; ++i)
#pragma unroll
        for (int j = 0; j < 4; ++j) acc[i][j] = (f32x4){0.f, 0.f, 0.f, 0.f};

    constexpr int nt = K / 32;
    STAGE(0, 0);
    STAGE(1, 32);

    for (int t = 0; t < nt; ++t) {
        if (t + 2 < nt) {
            STAGE((t + 2) % 3, (t + 2) * 32);
            asm volatile("s_waitcnt vmcnt(8)" ::: "memory");
        } else if (t + 1 < nt) {
            asm volatile("s_waitcnt vmcnt(4)" ::: "memory");
        } else {
            asm volatile("s_waitcnt vmcnt(0)" ::: "memory");
        }
        __builtin_amdgcn_s_barrier();
        __builtin_amdgcn_sched_barrier(0);

        const __hip_bfloat16* base = sm + (t % 3) * 16384;
        bf16x8 af[8], bfr[4];
#pragma unroll
        for (int i = 0; i < 8; ++i)
            af[i] = *reinterpret_cast<const bf16x8*>(base + aoff + i * 512);
#pragma unroll
        for (int j = 0; j < 4; ++j)
            bfr[j] = *reinterpret_cast<const bf16x8*>(base + boff + j * 512);

        __builtin_amdgcn_s_setprio(1);
#pragma unroll
        for (int i = 0; i < 8; ++i)
#pragma unroll
            for (int j = 0; j < 4; ++j)
                acc[i][j] = __builtin_amdgcn_mfma_f32_16x16x32_bf16(af[i], bfr[j], acc[i][j], 0, 0, 0);
        __builtin_amdgcn_s_setprio(0);
        __builtin_amdgcn_sched_barrier(0);
        __builtin_amdgcn_s_barrier();
    }

    // ---- epilogue: BN + LeakyReLU (+ xq for MODE 1) ----
    const int bq = row0 >> 11;  // batch index (tile rows within one batch)
#pragma unroll
    for (int j = 0; j < 4; ++j) {
        const int c = col0 + wn * 64 + j * 16 + lr;
        const float scl = Gg[c] * rsqrtf(Gv[c] + 1e-5f);
        const float tcn = Gb[c] - Gm[c] * scl;
        float xqv = 0.f;
        if constexpr (MODE == 1) xqv = xq[bq * 2048 + c];
#pragma unroll
        for (int i = 0; i < 8; ++i) {
            const int r = row0 + wm * 128 + i * 16 + kg * 4;
#pragma unroll
            for (int rI = 0; rI < 4; ++rI) {
                float val = acc[i][j][rI] * scl + tcn;
                val = LRELU(val) + xqv;
                out[(size_t)(r + rI) * N + c] = __float2bfloat16(val);
            }
        }
    }
}

// ---------------- GEMM3 (M x 64, K=512) fused with layer-4 + bn4 ----------
__global__ __launch_bounds__(256)
void gemm3_l4(const __hip_bfloat16* __restrict__ A,    // s2b [M,512]
              const __hip_bfloat16* __restrict__ W3b,  // [64,512]
              const float* __restrict__ W4,            // [64]
              const float* __restrict__ g3, const float* __restrict__ b3,
              const float* __restrict__ m3, const float* __restrict__ v3,
              const float* __restrict__ g4, const float* __restrict__ b4,
              const float* __restrict__ m4, const float* __restrict__ v4,
              float* __restrict__ logits) {
    const int lane = threadIdx.x & 63;
    const int wv = threadIdx.x >> 6;
    const int row0 = blockIdx.x * 128 + wv * 32;
    const int lr = lane & 15, kg = lane >> 4;

    f32x4 acc[2][4];
#pragma unroll
    for (int i = 0; i < 2; ++i)
#pragma unroll
        for (int j = 0; j < 4; ++j) acc[i][j] = (f32x4){0.f, 0.f, 0.f, 0.f};

    for (int k = 0; k < 512; k += 32) {
        const int kk = k + kg * 8;
        bf16x8 a[2], b[4];
#pragma unroll
        for (int i = 0; i < 2; ++i)
            a[i] = *reinterpret_cast<const bf16x8*>(A + (size_t)(row0 + i * 16 + lr) * 512 + kk);
#pragma unroll
        for (int j = 0; j < 4; ++j)
            b[j] = *reinterpret_cast<const bf16x8*>(W3b + (size_t)(j * 16 + lr) * 512 + kk);
#pragma unroll
        for (int i = 0; i < 2; ++i)
#pragma unroll
            for (int j = 0; j < 4; ++j)
                acc[i][j] = __builtin_amdgcn_mfma_f32_16x16x32_bf16(a[i], b[j], acc[i][j], 0, 0, 0);
    }

    const float sc4 = g4[0] * rsqrtf(v4[0] + 1e-5f);
    const float tc4 = b4[0] - m4[0] * sc4;
#pragma unroll
    for (int i = 0; i < 2; ++i) {
        float t[4] = {0.f, 0.f, 0.f, 0.f};
#pragma unroll
        for (int j = 0; j < 4; ++j) {
            const int c = j * 16 + lr;
            const float sc = g3[c] * rsqrtf(v3[c] + 1e-5f);
            const float tc = b3[c] - m3[c] * sc;
            const float w4c = W4[c];
#pragma unroll
            for (int rI = 0; rI < 4; ++rI) {
                float v = acc[i][j][rI] * sc + tc;
                t[rI] += LRELU(v) * w4c;
            }
        }
#pragma unroll
        for (int m = 1; m < 16; m <<= 1)
#pragma unroll
            for (int rI = 0; rI < 4; ++rI) t[rI] += __shfl_xor(t[rI], m, 64);
        if (lr == 0) {
#pragma unroll
            for (int rI = 0; rI < 4; ++rI) {
                float lg = t[rI] * sc4 + tc4;
                logits[row0 + i * 16 + kg * 4 + rI] = LRELU(lg);
            }
        }
    }
}

// ---------------- softmax over N=2048 per batch ----------------------------
__global__ void softmax2048(const float* __restrict__ logits, float* __restrict__ scores) {
    __shared__ float sh[2048];
    __shared__ float red[256];
    const int b = blockIdx.x, tid = threadIdx.x;
    float lmax = -1e30f;
#pragma unroll
    for (int it = 0; it < 8; ++it) {
        const int n = tid + it * 256;
        float v = logits[b * 2048 + n];
        sh[n] = v;
        lmax = fmaxf(lmax, v);
    }
    red[tid] = lmax;
    __syncthreads();
    for (int s = 128; s > 0; s >>= 1) {
        if (tid < s) red[tid] = fmaxf(red[tid], red[tid + s]);
        __syncthreads();
    }
    const float gmax = red[0];
    __syncthreads();
    float lsum = 0.f;
#pragma unroll
    for (int it = 0; it < 8; ++it) {
        const int n = tid + it * 256;
        float e = expf(sh[n] - gmax);
        sh[n] = e;
        lsum += e;
    }
    red[tid] = lsum;
    __syncthreads();
    for (int s = 128; s > 0; s >>= 1) {
        if (tid < s) red[tid] += red[tid + s];
        __syncthreads();
    }
    const float inv = 1.f / red[0];
#pragma unroll
    for (int it = 0; it < 8; ++it) {
        const int n = tid + it * 256;
        scores[b * 2048 + n] = sh[n] * inv;
    }
}

// ---------------- pooling over features, then subtract xq ------------------
// out[b,e] = sum_n features[b,n,e]*scores[b,n] - xq[b,e]   (sum scores = 1)
__global__ void pool_partial(const __hip_bfloat16* __restrict__ feats,
                             const float* __restrict__ scores,
                             float* __restrict__ partial) {
    const int b = blockIdx.y, nc = blockIdx.x;  // 32 chunks of 64 rows
    const int e0 = threadIdx.x * 8;
    float acc[8] = {0, 0, 0, 0, 0, 0, 0, 0};
    const size_t base = ((size_t)b * 2048 + nc * 64) * 2048;
    for (int i = 0; i < 64; ++i) {
        const float sc = scores[b * 2048 + nc * 64 + i];
        bf16x8 v = *reinterpret_cast<const bf16x8*>(feats + base + (size_t)i * 2048 + e0);
#pragma unroll
        for (int j = 0; j < 8; ++j) acc[j] += sc * (float)v[j];
    }
    float* p = partial + ((size_t)(b * 32 + nc)) * 2048 + e0;
#pragma unroll
    for (int j = 0; j < 8; ++j) p[j] = acc[j];
}

__global__ void pool_reduce(const float* __restrict__ partial,
                            const float* __restrict__ xq,
                            float* __restrict__ out) {
    const int i = blockIdx.x * blockDim.x + threadIdx.x;  // 0..32767
    const int b = i >> 11, e = i & 2047;
    float s = 0.f;
#pragma unroll
    for (int nc = 0; nc < 32; ++nc) s += partial[((size_t)(b * 32 + nc)) * 2048 + e];
    out[i] = s - xq[i];
}

// ---------------------------------------------------------------------------
extern "C" void kernel_launch(void* const* d_in, const int* in_sizes, int n_in,
                              void* d_out, int out_size, void* d_ws, size_t ws_size,
                              hipStream_t stream) {
    const float* xq = (const float*)d_in[0];
    const float* xk = (const float*)d_in[1];
    const float* W1 = (const float*)d_in[2];
    const float* W2 = (const float*)d_in[3];
    const float* W3 = (const float*)d_in[4];
    const float* W4 = (const float*)d_in[5];
    const float* g1 = (const float*)d_in[6], *b1 = (const float*)d_in[7];
    const float* m1 = (const float*)d_in[8], *v1 = (const float*)d_in[9];
    const float* g2 = (const float*)d_in[10], *b2 = (const float*)d_in[11];
    const float* m2 = (const float*)d_in[12], *v2 = (const float*)d_in[13];
    const float* g3 = (const float*)d_in[14], *b3 = (const float*)d_in[15];
    const float* m3 = (const float*)d_in[16], *v3 = (const float*)d_in[17];
    const float* g4 = (const float*)d_in[18], *b4 = (const float*)d_in[19];
    const float* m4 = (const float*)d_in[20], *v4 = (const float*)d_in[21];

    const int M = 32768;  // B*N = 16*2048

    char* ws = (char*)d_ws;
    size_t off = 0;
    auto alloc = [&](size_t bytes) {
        void* p = ws + off;
        off += (bytes + 255) & ~(size_t)255;
        return p;
    };
    __hip_bfloat16* xkb   = (__hip_bfloat16*)alloc((size_t)M * 512 * 2);
    __hip_bfloat16* w1b   = (__hip_bfloat16*)alloc((size_t)2048 * 512 * 2);
    __hip_bfloat16* w2b   = (__hip_bfloat16*)alloc((size_t)512 * 2048 * 2);
    __hip_bfloat16* w3b   = (__hip_bfloat16*)alloc((size_t)64 * 512 * 2);
    __hip_bfloat16* featb = (__hip_bfloat16*)alloc((size_t)M * 2048 * 2);
    __hip_bfloat16* s2b   = (__hip_bfloat16*)alloc((size_t)M * 512 * 2);
    float* logits         = (float*)alloc((size_t)M * 4);
    float* scores         = (float*)alloc((size_t)16 * 2048 * 4);
    float* partial        = (float*)alloc((size_t)16 * 32 * 2048 * 4);

    // converts
    cvt_f32_bf16<<<4096, 256, 0, stream>>>(xk, xkb, M * 512 / 4);
    cvt_f32_bf16<<<1024, 256, 0, stream>>>(W1, w1b, 2048 * 512 / 4);
    cvt_f32_bf16<<<1024, 256, 0, stream>>>(W2, w2b, 512 * 2048 / 4);
    cvt_f32_bf16<<<32, 256, 0, stream>>>(W3, w3b, 64 * 512 / 4);

    // GEMM1: features = lrelu(bn1(xk @ W1^T)) + xq   [M,2048] bf16
    gemm256<2048, 512, 1><<<1024, 512, 0, stream>>>(
        xkb, w1b, xq, featb, g1, b1, m1, v1);

    // GEMM2: s2 = lrelu(bn2(features @ W2^T))        [M,512] bf16
    gemm256<512, 2048, 2><<<256, 512, 0, stream>>>(
        featb, w2b, nullptr, s2b, g2, b2, m2, v2);

    // GEMM3 + layer4: logits [M] f32
    gemm3_l4<<<256, 256, 0, stream>>>(s2b, w3b, W4,
                                      g3, b3, m3, v3, g4, b4, m4, v4, logits);

    // softmax over N per batch
    softmax2048<<<16, 256, 0, stream>>>(logits, scores);

    // pooling (+ subtract xq)
    pool_partial<<<dim3(32, 16), 256, 0, stream>>>(featb, scores, partial);
    pool_reduce<<<128, 256, 0, stream>>>(partial, xq, (float*)d_out);
}

// Round 4
// 238.466 us; speedup vs baseline: 2.4435x; 1.0273x over previous
//
#include <hip/hip_runtime.h>
#include <hip/hip_bf16.h>

typedef __bf16 bf16x8 __attribute__((ext_vector_type(8)));
typedef float f32x4 __attribute__((ext_vector_type(4)));
typedef __attribute__((address_space(3))) void lds_void_t;
typedef __attribute__((address_space(1))) void gbl_void_t;

#define LRELU(x) ((x) >= 0.f ? (x) : 0.2f * (x))

__device__ __forceinline__ void gload16(void* lds_uniform, const void* gsrc) {
    __builtin_amdgcn_global_load_lds((const gbl_void_t*)gsrc, (lds_void_t*)lds_uniform,
                                     16, 0, 0);
}

__device__ __forceinline__ unsigned short f2u(float f) {
    __hip_bfloat16 h = __float2bfloat16(f);
    return reinterpret_cast<unsigned short&>(h);
}

// ---------------- f32 -> bf16 convert (vector4) ----------------------------
__global__ void cvt_f32_bf16(const float* __restrict__ in,
                             __hip_bfloat16* __restrict__ out, int n4) {
    int stride = gridDim.x * blockDim.x;
    for (int i = blockIdx.x * blockDim.x + threadIdx.x; i < n4; i += stride) {
        float4 v = reinterpret_cast<const float4*>(in)[i];
        ushort4 o;
        o.x = f2u(v.x); o.y = f2u(v.y); o.z = f2u(v.z); o.w = f2u(v.w);
        reinterpret_cast<ushort4*>(out)[i] = o;
    }
}

// ---------------- 256x256 tile GEMM, BK=32, triple-buffer, phase-split -----
// 8 waves (2M x 4N), per-wave output 128x64 (8x4 fragments 16x16x32 bf16).
// LDS: 3 buffers x (A 8192 + B 8192 elements) = 96 KB.
// Per K-tile: ONE barrier + ONE counted vmcnt(4); two phases:
//   A: stage kt+2 A-halves (2 gload_lds) | ds_read af[0..3],bfr[0..3] | 16 MFMA
//   B: stage kt+2 B-halves (2 gload_lds) | ds_read af[4..7]           | 16 MFMA
// Ledger: RAW  - vmcnt(4)+barrier at iter t start => only tile t+1's 4 loads
//               outstanding per wave, tile t landed (wave-uniform order).
//         WAR  - stage at iter t writes buf (t+2)%3, last read iter t-1,
//               separated by iter-t barrier (reads drained via MFMA deps).
//         DMA  - loads to that buf are from iter t-3 => landed under vmcnt(4).
// MODE 1: out = bf16( lrelu(bn(A@B^T)) + xq[b][col] )   (features)
// MODE 2: out = bf16( lrelu(bn(A@B^T)) )                (s2)
template <int N, int K, int MODE>
__global__ __launch_bounds__(512, 2)
void gemm256(const __hip_bfloat16* __restrict__ A,
             const __hip_bfloat16* __restrict__ Bw,
             const float* __restrict__ xq,
             __hip_bfloat16* __restrict__ out,
             const float* __restrict__ Gg, const float* __restrict__ Gb,
             const float* __restrict__ Gm, const float* __restrict__ Gv) {
    __shared__ __hip_bfloat16 sm[3 * 16384];

    // XCD-aware block swizzle (nwg % 8 == 0 guaranteed by launch config)
    const int nwg = gridDim.x;
    const int cpx = nwg >> 3;
    const int bid = blockIdx.x;
    const int orig = (bid & 7) * cpx + (bid >> 3);
    constexpr int NCB = N / 256;
    const int rowblk = orig / NCB;
    const int colblk = orig % NCB;
    const int row0 = rowblk * 256, col0 = colblk * 256;

    const int tid = threadIdx.x;
    const int lane = tid & 63;
    const int wv = tid >> 6;          // 0..7
    const int wm = wv >> 2, wn = wv & 3;
    const int lr = lane & 15, kg = lane >> 4;

    // ---- staging source addresses (pre-swizzled global chunks) ----
    const int srow = tid >> 2;        // dest row (mod 128)
    const int sc = tid & 3;           // dest 16B-chunk position
    const int kch = ((sc ^ ((srow >> 1) & 3)) << 3);  // source k-chunk (elements)
    const __hip_bfloat16* As0 = A + (size_t)(row0 + srow) * K + kch;
    const __hip_bfloat16* As1 = A + (size_t)(row0 + 128 + srow) * K + kch;
    const __hip_bfloat16* Bs0 = Bw + (size_t)(col0 + srow) * K + kch;
    const __hip_bfloat16* Bs1 = Bw + (size_t)(col0 + 128 + srow) * K + kch;

    auto STAGE_A = [&](int b, int k0) {
        __hip_bfloat16* la = sm + b * 16384 + wv * 512;  // per-wave uniform base
        gload16(la,        As0 + k0);
        gload16(la + 4096, As1 + k0);
    };
    auto STAGE_B = [&](int b, int k0) {
        __hip_bfloat16* lb = sm + b * 16384 + 8192 + wv * 512;
        gload16(lb,        Bs0 + k0);
        gload16(lb + 4096, Bs1 + k0);
    };

    // ---- ds_read fragment offsets (swizzled chunk) ----
    const int f = (lr >> 1) & 3;
    const int koff = ((kg ^ f) << 3);
    const int aoff = (wm * 128 + lr) * 32 + koff;          // A: elements
    const int boff = 8192 + (wn * 64 + lr) * 32 + koff;    // B: elements

    f32x4 acc[8][4];
#pragma unroll
    for (int i = 0; i < 8; ++i)
#pragma unroll
        for (int j = 0; j < 4; ++j) acc[i][j] = (f32x4){0.f, 0.f, 0.f, 0.f};

    constexpr int nt = K / 32;
    STAGE_A(0, 0);  STAGE_B(0, 0);
    STAGE_A(1, 32); STAGE_B(1, 32);

    for (int t = 0; t < nt; ++t) {
        if (t + 1 < nt) {
            asm volatile("s_waitcnt vmcnt(4)" ::: "memory");
        } else {
            asm volatile("s_waitcnt vmcnt(0)" ::: "memory");
        }
        __builtin_amdgcn_s_barrier();
        __builtin_amdgcn_sched_barrier(0);

        const __hip_bfloat16* base = sm + (t % 3) * 16384;
        bf16x8 af[8], bfr[4];

        // ---- phase A ----
        if (t + 2 < nt) STAGE_A((t + 2) % 3, (t + 2) * 32);
#pragma unroll
        for (int i = 0; i < 4; ++i)
            af[i] = *reinterpret_cast<const bf16x8*>(base + aoff + i * 512);
#pragma unroll
        for (int j = 0; j < 4; ++j)
            bfr[j] = *reinterpret_cast<const bf16x8*>(base + boff + j * 512);
        __builtin_amdgcn_s_setprio(1);
#pragma unroll
        for (int i = 0; i < 4; ++i)
#pragma unroll
            for (int j = 0; j < 4; ++j)
                acc[i][j] = __builtin_amdgcn_mfma_f32_16x16x32_bf16(af[i], bfr[j], acc[i][j], 0, 0, 0);
        __builtin_amdgcn_s_setprio(0);
        __builtin_amdgcn_sched_barrier(0);

        // ---- phase B ----
        if (t + 2 < nt) STAGE_B((t + 2) % 3, (t + 2) * 32);
#pragma unroll
        for (int i = 4; i < 8; ++i)
            af[i] = *reinterpret_cast<const bf16x8*>(base + aoff + i * 512);
        __builtin_amdgcn_s_setprio(1);
#pragma unroll
        for (int i = 4; i < 8; ++i)
#pragma unroll
            for (int j = 0; j < 4; ++j)
                acc[i][j] = __builtin_amdgcn_mfma_f32_16x16x32_bf16(af[i], bfr[j], acc[i][j], 0, 0, 0);
        __builtin_amdgcn_s_setprio(0);
        __builtin_amdgcn_sched_barrier(0);
    }

    // ---- epilogue: BN + LeakyReLU (+ xq for MODE 1) ----
    const int bq = row0 >> 11;  // batch index (tile rows within one batch)
#pragma unroll
    for (int j = 0; j < 4; ++j) {
        const int c = col0 + wn * 64 + j * 16 + lr;
        const float scl = Gg[c] * rsqrtf(Gv[c] + 1e-5f);
        const float tcn = Gb[c] - Gm[c] * scl;
        float xqv = 0.f;
        if constexpr (MODE == 1) xqv = xq[bq * 2048 + c];
#pragma unroll
        for (int i = 0; i < 8; ++i) {
            const int r = row0 + wm * 128 + i * 16 + kg * 4;
#pragma unroll
            for (int rI = 0; rI < 4; ++rI) {
                float val = acc[i][j][rI] * scl + tcn;
                val = LRELU(val) + xqv;
                out[(size_t)(r + rI) * N + c] = __float2bfloat16(val);
            }
        }
    }
}

// ---------------- GEMM3 (M x 64, K=512) fused with layer-4 + bn4 ----------
__global__ __launch_bounds__(256)
void gemm3_l4(const __hip_bfloat16* __restrict__ A,    // s2b [M,512]
              const __hip_bfloat16* __restrict__ W3b,  // [64,512]
              const float* __restrict__ W4,            // [64]
              const float* __restrict__ g3, const float* __restrict__ b3,
              const float* __restrict__ m3, const float* __restrict__ v3,
              const float* __restrict__ g4, const float* __restrict__ b4,
              const float* __restrict__ m4, const float* __restrict__ v4,
              float* __restrict__ logits) {
    const int lane = threadIdx.x & 63;
    const int wv = threadIdx.x >> 6;
    const int row0 = blockIdx.x * 128 + wv * 32;
    const int lr = lane & 15, kg = lane >> 4;

    f32x4 acc[2][4];
#pragma unroll
    for (int i = 0; i < 2; ++i)
#pragma unroll
        for (int j = 0; j < 4; ++j) acc[i][j] = (f32x4){0.f, 0.f, 0.f, 0.f};

    for (int k = 0; k < 512; k += 32) {
        const int kk = k + kg * 8;
        bf16x8 a[2], b[4];
#pragma unroll
        for (int i = 0; i < 2; ++i)
            a[i] = *reinterpret_cast<const bf16x8*>(A + (size_t)(row0 + i * 16 + lr) * 512 + kk);
#pragma unroll
        for (int j = 0; j < 4; ++j)
            b[j] = *reinterpret_cast<const bf16x8*>(W3b + (size_t)(j * 16 + lr) * 512 + kk);
#pragma unroll
        for (int i = 0; i < 2; ++i)
#pragma unroll
            for (int j = 0; j < 4; ++j)
                acc[i][j] = __builtin_amdgcn_mfma_f32_16x16x32_bf16(a[i], b[j], acc[i][j], 0, 0, 0);
    }

    const float sc4 = g4[0] * rsqrtf(v4[0] + 1e-5f);
    const float tc4 = b4[0] - m4[0] * sc4;
#pragma unroll
    for (int i = 0; i < 2; ++i) {
        float t[4] = {0.f, 0.f, 0.f, 0.f};
#pragma unroll
        for (int j = 0; j < 4; ++j) {
            const int c = j * 16 + lr;
            const float sc = g3[c] * rsqrtf(v3[c] + 1e-5f);
            const float tc = b3[c] - m3[c] * sc;
            const float w4c = W4[c];
#pragma unroll
            for (int rI = 0; rI < 4; ++rI) {
                float v = acc[i][j][rI] * sc + tc;
                t[rI] += LRELU(v) * w4c;
            }
        }
#pragma unroll
        for (int m = 1; m < 16; m <<= 1)
#pragma unroll
            for (int rI = 0; rI < 4; ++rI) t[rI] += __shfl_xor(t[rI], m, 64);
        if (lr == 0) {
#pragma unroll
            for (int rI = 0; rI < 4; ++rI) {
                float lg = t[rI] * sc4 + tc4;
                logits[row0 + i * 16 + kg * 4 + rI] = LRELU(lg);
            }
        }
    }
}

// ---------------- softmax over N=2048 per batch ----------------------------
__global__ void softmax2048(const float* __restrict__ logits, float* __restrict__ scores) {
    __shared__ float sh[2048];
    __shared__ float red[256];
    const int b = blockIdx.x, tid = threadIdx.x;
    float lmax = -1e30f;
#pragma unroll
    for (int it = 0; it < 8; ++it) {
        const int n = tid + it * 256;
        float v = logits[b * 2048 + n];
        sh[n] = v;
        lmax = fmaxf(lmax, v);
    }
    red[tid] = lmax;
    __syncthreads();
    for (int s = 128; s > 0; s >>= 1) {
        if (tid < s) red[tid] = fmaxf(red[tid], red[tid + s]);
        __syncthreads();
    }
    const float gmax = red[0];
    __syncthreads();
    float lsum = 0.f;
#pragma unroll
    for (int it = 0; it < 8; ++it) {
        const int n = tid + it * 256;
        float e = expf(sh[n] - gmax);
        sh[n] = e;
        lsum += e;
    }
    red[tid] = lsum;
    __syncthreads();
    for (int s = 128; s > 0; s >>= 1) {
        if (tid < s) red[tid] += red[tid + s];
        __syncthreads();
    }
    const float inv = 1.f / red[0];
#pragma unroll
    for (int it = 0; it < 8; ++it) {
        const int n = tid + it * 256;
        scores[b * 2048 + n] = sh[n] * inv;
    }
}

// ---------------- pooling over features, then subtract xq ------------------
// out[b,e] = sum_n features[b,n,e]*scores[b,n] - xq[b,e]   (sum scores = 1)
__global__ void pool_partial(const __hip_bfloat16* __restrict__ feats,
                             const float* __restrict__ scores,
                             float* __restrict__ partial) {
    const int b = blockIdx.y, nc = blockIdx.x;  // 32 chunks of 64 rows
    const int e0 = threadIdx.x * 8;
    float acc[8] = {0, 0, 0, 0, 0, 0, 0, 0};
    const size_t base = ((size_t)b * 2048 + nc * 64) * 2048;
    for (int i = 0; i < 64; ++i) {
        const float sc = scores[b * 2048 + nc * 64 + i];
        bf16x8 v = *reinterpret_cast<const bf16x8*>(feats + base + (size_t)i * 2048 + e0);
#pragma unroll
        for (int j = 0; j < 8; ++j) acc[j] += sc * (float)v[j];
    }
    float* p = partial + ((size_t)(b * 32 + nc)) * 2048 + e0;
#pragma unroll
    for (int j = 0; j < 8; ++j) p[j] = acc[j];
}

__global__ void pool_reduce(const float* __restrict__ partial,
                            const float* __restrict__ xq,
                            float* __restrict__ out) {
    const int i = blockIdx.x * blockDim.x + threadIdx.x;  // 0..32767
    const int b = i >> 11, e = i & 2047;
    float s = 0.f;
#pragma unroll
    for (int nc = 0; nc < 32; ++nc) s += partial[((size_t)(b * 32 + nc)) * 2048 + e];
    out[i] = s - xq[i];
}

// ---------------------------------------------------------------------------
extern "C" void kernel_launch(void* const* d_in, const int* in_sizes, int n_in,
                              void* d_out, int out_size, void* d_ws, size_t ws_size,
                              hipStream_t stream) {
    const float* xq = (const float*)d_in[0];
    const float* xk = (const float*)d_in[1];
    const float* W1 = (const float*)d_in[2];
    const float* W2 = (const float*)d_in[3];
    const float* W3 = (const float*)d_in[4];
    const float* W4 = (const float*)d_in[5];
    const float* g1 = (const float*)d_in[6], *b1 = (const float*)d_in[7];
    const float* m1 = (const float*)d_in[8], *v1 = (const float*)d_in[9];
    const float* g2 = (const float*)d_in[10], *b2 = (const float*)d_in[11];
    const float* m2 = (const float*)d_in[12], *v2 = (const float*)d_in[13];
    const float* g3 = (const float*)d_in[14], *b3 = (const float*)d_in[15];
    const float* m3 = (const float*)d_in[16], *v3 = (const float*)d_in[17];
    const float* g4 = (const float*)d_in[18], *b4 = (const float*)d_in[19];
    const float* m4 = (const float*)d_in[20], *v4 = (const float*)d_in[21];

    const int M = 32768;  // B*N = 16*2048

    char* ws = (char*)d_ws;
    size_t off = 0;
    auto alloc = [&](size_t bytes) {
        void* p = ws + off;
        off += (bytes + 255) & ~(size_t)255;
        return p;
    };
    __hip_bfloat16* xkb   = (__hip_bfloat16*)alloc((size_t)M * 512 * 2);
    __hip_bfloat16* w1b   = (__hip_bfloat16*)alloc((size_t)2048 * 512 * 2);
    __hip_bfloat16* w2b   = (__hip_bfloat16*)alloc((size_t)512 * 2048 * 2);
    __hip_bfloat16* w3b   = (__hip_bfloat16*)alloc((size_t)64 * 512 * 2);
    __hip_bfloat16* featb = (__hip_bfloat16*)alloc((size_t)M * 2048 * 2);
    __hip_bfloat16* s2b   = (__hip_bfloat16*)alloc((size_t)M * 512 * 2);
    float* logits         = (float*)alloc((size_t)M * 4);
    float* scores         = (float*)alloc((size_t)16 * 2048 * 4);
    float* partial        = (float*)alloc((size_t)16 * 32 * 2048 * 4);

    // converts
    cvt_f32_bf16<<<4096, 256, 0, stream>>>(xk, xkb, M * 512 / 4);
    cvt_f32_bf16<<<1024, 256, 0, stream>>>(W1, w1b, 2048 * 512 / 4);
    cvt_f32_bf16<<<1024, 256, 0, stream>>>(W2, w2b, 512 * 2048 / 4);
    cvt_f32_bf16<<<32, 256, 0, stream>>>(W3, w3b, 64 * 512 / 4);

    // GEMM1: features = lrelu(bn1(xk @ W1^T)) + xq   [M,2048] bf16
    gemm256<2048, 512, 1><<<1024, 512, 0, stream>>>(
        xkb, w1b, xq, featb, g1, b1, m1, v1);

    // GEMM2: s2 = lrelu(bn2(features @ W2^T))        [M,512] bf16
    gemm256<512, 2048, 2><<<256, 512, 0, stream>>>(
        featb, w2b, nullptr, s2b, g2, b2, m2, v2);

    // GEMM3 + layer4: logits [M] f32
    gemm3_l4<<<256, 256, 0, stream>>>(s2b, w3b, W4,
                                      g3, b3, m3, v3, g4, b4, m4, v4, logits);

    // softmax over N per batch
    softmax2048<<<16, 256, 0, stream>>>(logits, scores);

    // pooling (+ subtract xq)
    pool_partial<<<dim3(32, 16), 256, 0, stream>>>(featb, scores, partial);
    pool_reduce<<<128, 256, 0, stream>>>(partial, xq, (float*)d_out);
}